// Round 4
// baseline (2532.687 us; speedup 1.0000x reference)
//
#include <hip/hip_runtime.h>
#include <hip/hip_fp16.h>

// GRU: T=2048, B=64, I=H=256.  out = ([T,B,H] f32, initial hx)
//
//  1) cvt_init: f32->f16 weight copies into ws, h_state := hx, write hx tail of d_out.
//  2) gi_gemm:  gi = x @ x2h_w^T + (x2h_b + h2h_b[r,z gates]) via f16 MFMA, f16 in ws.
//  3) gru_rec:  64 WGs (one per batch) x 512 threads, K-split by 2. Thread (half, j)
//               owns the K-slice [half*128, half*128+128) of h2h_w rows {j, j+256, j+512}
//               = 48 uint4 = 192 VGPRs. The pin asm is INSIDE the time loop: a volatile
//               "+v" asm each iteration makes remat illegal (R3's one-time pin was
//               defeated by remat-from-global -> L2-BW-bound). 192+~40 regs fits the
//               256 arch cap at launch_bounds(512,1). 2 barriers/step, gi prefetch 1 deep.

typedef _Float16 half2v __attribute__((ext_vector_type(2)));
typedef _Float16 half8  __attribute__((ext_vector_type(8)));
typedef float    f32x4  __attribute__((ext_vector_type(4)));
typedef unsigned int uint4v __attribute__((ext_vector_type(4)));

#define T_SEQ 2048
#define BATCH 64
#define HDIM  256
#define G3    768   // 3*H

__device__ __forceinline__ half2v u2h(unsigned int u) {
    union { unsigned int u; half2v h; } c; c.u = u; return c.h;
}

__device__ __forceinline__ float fdot2(half2v a, half2v b, float c) {
#if __has_builtin(__builtin_amdgcn_fdot2)
    return __builtin_amdgcn_fdot2(a, b, c, false);
#else
    return c + (float)a[0] * (float)b[0] + (float)a[1] * (float)b[1];
#endif
}

__device__ __forceinline__ float sigmoid_f(float x) {
    return 1.f / (1.f + __expf(-x));
}
__device__ __forceinline__ float tanh_f(float x) {
    float e = __expf(2.f * x);
    return 1.f - 2.f / (e + 1.f);
}

// ---------------------------------------------------------------- cvt_init
__global__ void cvt_init(const float* __restrict__ x2h_w, const float* __restrict__ h2h_w,
                         const float* __restrict__ hx,
                         _Float16* __restrict__ wx16, _Float16* __restrict__ wh16,
                         float* __restrict__ hstate, float* __restrict__ out_tail) {
    int i = blockIdx.x * 256 + threadIdx.x;
    if (i < G3 * HDIM) {
        wx16[i] = (_Float16)x2h_w[i];
        wh16[i] = (_Float16)h2h_w[i];
    }
    if (i < BATCH * HDIM) {
        float v = hx[i];
        hstate[i] = v;
        out_tail[i] = v;   // second output = INITIAL hx
    }
}

// ---------------------------------------------------------------- gi_gemm
// mfma_f32_16x16x32_f16: A lane holds A[row=l&15, k=(l>>4)*8+i];
// B lane holds B[k=(l>>4)*8+i, col=l&15]; D lane holds C[row=(l>>4)*4+r, col=l&15].
// Bias: x2h_b[col] + (col<512 ? h2h_b[col] : 0)  — folds the r/z h2h biases in.
__global__ __launch_bounds__(256) void gi_gemm(const float* __restrict__ x,
                                               const _Float16* __restrict__ wx,
                                               const float* __restrict__ bx,
                                               const float* __restrict__ bh,
                                               _Float16* __restrict__ gi,
                                               int row_base) {
    const int lane  = threadIdx.x & 63;
    const int wave  = threadIdx.x >> 6;
    const int l15   = lane & 15;
    const int kslot = lane >> 4;               // 0..3
    const int row0  = row_base + blockIdx.x * 256 + wave * 64;

    half8 a[4][8];
    #pragma unroll
    for (int s = 0; s < 4; ++s) {
        const float* xr = x + (size_t)(row0 + s * 16 + l15) * HDIM + kslot * 8;
        #pragma unroll
        for (int kt = 0; kt < 8; ++kt) {
            float4 lo = *(const float4*)(xr + kt * 32);
            float4 hi = *(const float4*)(xr + kt * 32 + 4);
            half8 v;
            v[0] = (_Float16)lo.x; v[1] = (_Float16)lo.y; v[2] = (_Float16)lo.z; v[3] = (_Float16)lo.w;
            v[4] = (_Float16)hi.x; v[5] = (_Float16)hi.y; v[6] = (_Float16)hi.z; v[7] = (_Float16)hi.w;
            a[s][kt] = v;
        }
    }

    for (int nt = 0; nt < 48; ++nt) {
        half8 b[8];
        const _Float16* wr = wx + (size_t)(nt * 16 + l15) * HDIM + kslot * 8;
        #pragma unroll
        for (int kt = 0; kt < 8; ++kt) b[kt] = *(const half8*)(wr + kt * 32);
        const int   col  = nt * 16 + l15;
        float bias = bx[col];
        if (col < 512) bias += bh[col];
        #pragma unroll
        for (int s = 0; s < 4; ++s) {
            f32x4 acc = {0.f, 0.f, 0.f, 0.f};
            #pragma unroll
            for (int kt = 0; kt < 8; ++kt)
                acc = __builtin_amdgcn_mfma_f32_16x16x32_f16(a[s][kt], b[kt], acc, 0, 0, 0);
            #pragma unroll
            for (int r = 0; r < 4; ++r) {
                int rowl = (row0 - row_base) + s * 16 + kslot * 4 + r;
                gi[(size_t)rowl * G3 + col] = (_Float16)(acc[r] + bias);
            }
        }
    }
}

// ---------------------------------------------------------------- gru_rec
// 64 WGs x 512 threads. K-split-2: thread (half=tid>>8, j=tid&255) owns the
// half-K slices of h2h_w rows j / j+256 / j+512 -> 192 register-resident VGPRs,
// pinned EVERY iteration so the compiler cannot rematerialize the loads.
__global__ __launch_bounds__(512, 1) void gru_rec(const _Float16* __restrict__ gi,
                                                  const _Float16* __restrict__ wh,
                                                  const float* __restrict__ bh,
                                                  const float* __restrict__ hx,
                                                  float* __restrict__ hstate,
                                                  float* __restrict__ out,
                                                  int t_start, int t_len) {
    __shared__ __align__(16) _Float16 hbuf[2][HDIM];
    __shared__ float psum[3][HDIM];

    const int tid  = threadIdx.x;
    const int half = tid >> 8;            // 0: K in [0,128), 1: K in [128,256)
    const int j    = tid & 255;
    const int b    = blockIdx.x;

    // 3 half-rows -> 48 x uint4v = 192 VGPRs
    uint4v wr[16], wz[16], wn[16];
    {
        const uint4v* pr = (const uint4v*)(wh + (size_t)j * HDIM + half * 128);
        const uint4v* pz = (const uint4v*)(wh + (size_t)(j + 256) * HDIM + half * 128);
        const uint4v* pn = (const uint4v*)(wh + (size_t)(j + 512) * HDIM + half * 128);
        #pragma unroll
        for (int i = 0; i < 16; ++i) { wr[i] = pr[i]; wz[i] = pz[i]; wn[i] = pn[i]; }
    }

    // h2h n-gate bias (r/z biases are folded into gi by gi_gemm)
    const float bn = bh[j + 512];

    float h_old = 0.f;
    if (half == 0) {
        h_old = (t_start == 0) ? hx[b * HDIM + j] : hstate[b * HDIM + j];
        hbuf[0][j] = (_Float16)h_old;
    }
    __syncthreads();

    const size_t STEP  = (size_t)BATCH * G3;
    const size_t OSTEP = (size_t)BATCH * HDIM;
    const _Float16* gp = gi + (size_t)b * G3 + j;   // advanced by STEP each iter
    float* outp = out + ((size_t)t_start * BATCH + b) * HDIM + j;

    // 1-deep prefetch: holds gi for the CURRENT step
    float cr = 0.f, cz = 0.f, cn = 0.f;
    if (half == 0) {
        cr = (float)gp[0];
        cz = (float)gp[256];
        cn = (float)gp[512];
    }

    int p = 0;
    for (int tt = 0; tt < t_len; ++tt) {
        // Pin the weight registers EVERY iteration: remat from global is now illegal.
        #pragma unroll
        for (int i = 0; i < 16; ++i)
            asm volatile("" : "+v"(wr[i]), "+v"(wz[i]), "+v"(wn[i]));

        const float ur = cr, uz = cz, un = cn;
        if (half == 0 && tt + 1 < t_len) {
            const _Float16* gn2 = gp + STEP;
            cr = (float)gn2[0];
            cz = (float)gn2[256];
            cn = (float)gn2[512];
        }
        gp += STEP;

        float ar = 0.f, az = 0.f, an = 0.f;
        const uint4v* hp = (const uint4v*)&hbuf[p][half * 128];
        #pragma unroll
        for (int i = 0; i < 16; ++i) {
            uint4v hv = hp[i];
            ar = fdot2(u2h(wr[i][0]), u2h(hv[0]), ar);
            ar = fdot2(u2h(wr[i][1]), u2h(hv[1]), ar);
            ar = fdot2(u2h(wr[i][2]), u2h(hv[2]), ar);
            ar = fdot2(u2h(wr[i][3]), u2h(hv[3]), ar);
            az = fdot2(u2h(wz[i][0]), u2h(hv[0]), az);
            az = fdot2(u2h(wz[i][1]), u2h(hv[1]), az);
            az = fdot2(u2h(wz[i][2]), u2h(hv[2]), az);
            az = fdot2(u2h(wz[i][3]), u2h(hv[3]), az);
            an = fdot2(u2h(wn[i][0]), u2h(hv[0]), an);
            an = fdot2(u2h(wn[i][1]), u2h(hv[1]), an);
            an = fdot2(u2h(wn[i][2]), u2h(hv[2]), an);
            an = fdot2(u2h(wn[i][3]), u2h(hv[3]), an);
        }
        if (half) { psum[0][j] = ar; psum[1][j] = az; psum[2][j] = an; }
        __syncthreads();
        if (!half) {
            float r = sigmoid_f(ar + psum[0][j] + ur);
            float z = sigmoid_f(az + psum[1][j] + uz);
            float n = tanh_f(un + r * (an + psum[2][j] + bn));
            float hnew = (1.f - z) * n + z * h_old;
            *outp = hnew;
            h_old = hnew;
            hbuf[p ^ 1][j] = (_Float16)hnew;
        }
        outp += OSTEP;
        __syncthreads();
        p ^= 1;
    }
    if (!half) hstate[b * HDIM + j] = h_old;
}

// ---------------------------------------------------------------- host
extern "C" void kernel_launch(void* const* d_in, const int* in_sizes, int n_in,
                              void* d_out, int out_size, void* d_ws, size_t ws_size,
                              hipStream_t stream) {
    const float* x     = (const float*)d_in[0];
    const float* hx    = (const float*)d_in[1];
    const float* x2h_w = (const float*)d_in[2];
    const float* h2h_w = (const float*)d_in[3];
    const float* x2h_b = (const float*)d_in[4];
    const float* h2h_b = (const float*)d_in[5];
    float* out = (float*)d_out;

    char* ws = (char*)d_ws;
    _Float16* wx16   = (_Float16*)ws;                    // 393216 B
    _Float16* wh16   = (_Float16*)(ws + 393216);         // 393216 B
    float*    hstate = (float*)(ws + 786432);            // 65536 B
    _Float16* gi     = (_Float16*)(ws + 851968);

    size_t gi_cap_elems = (ws_size > 851968) ? (ws_size - 851968) / 2 : 0;
    int CT = T_SEQ;
    while ((size_t)CT * BATCH * G3 > gi_cap_elems && CT > 64) CT >>= 1;

    cvt_init<<<768, 256, 0, stream>>>(x2h_w, h2h_w, hx, wx16, wh16, hstate,
                                      out + (size_t)T_SEQ * BATCH * HDIM);

    for (int t0 = 0; t0 < T_SEQ; t0 += CT) {
        int rows = CT * BATCH;
        gi_gemm<<<rows / 256, 256, 0, stream>>>(x, wx16, x2h_b, h2h_b, gi, t0 * BATCH);
        gru_rec<<<BATCH, 512, 0, stream>>>(gi, wh16, h2h_b, hx, hstate, out, t0, CT);
    }
}